// Round 1
// baseline (186.339 us; speedup 1.0000x reference)
//
#include <hip/hip_runtime.h>
#include <hip/hip_bf16.h>

#define S_DIM 128
#define R_DIM 256
#define CM    256
#define H_DIM 32
#define CZ    128

typedef short s8v  __attribute__((ext_vector_type(8)));   // 8 bf16 in 4 VGPRs
typedef float f32x4 __attribute__((ext_vector_type(4)));
using bf16 = __hip_bfloat16;

static __device__ __forceinline__ unsigned short bf16_bits(float f) {
  return __builtin_bit_cast(unsigned short, __float2bfloat16(f));
}

// ---------------------------------------------------------------------------
// Kernel 1: fused LayerNorm + linear + mask, writing transposed bf16 output
// aT[p][s] with p = r*32 + h  (so GEMM1 K(=s) is contiguous per row).
// Block: 256 thr = 4 waves; handles 8 rows (same r, s = s0..s0+7) of ONE matrix.
// ---------------------------------------------------------------------------
__global__ __launch_bounds__(256) void opm_proj(
    const float* __restrict__ m1, const float* __restrict__ m2,
    const float* __restrict__ ln1w, const float* __restrict__ ln1b,
    const float* __restrict__ ln2w, const float* __restrict__ ln2b,
    const float* __restrict__ w1, const float* __restrict__ b1,
    const float* __restrict__ w2, const float* __restrict__ b2,
    const float* __restrict__ mask1, const float* __restrict__ mask2,
    bf16* __restrict__ aT, bf16* __restrict__ bT)
{
  __shared__ float xnb[8][CM];            // 8KB normalized rows
  __shared__ float part[8][4][H_DIM];     // 4KB per-wave partials
  __shared__ unsigned short valsb[8][H_DIM]; // bf16 bits

  const int mat = blockIdx.y;
  const float* __restrict__ m    = mat ? m2   : m1;
  const float* __restrict__ lnw  = mat ? ln2w : ln1w;
  const float* __restrict__ lnbp = mat ? ln2b : ln1b;
  const float* __restrict__ w    = mat ? w2   : w1;
  const float* __restrict__ bias = mat ? b2   : b1;
  const float* __restrict__ mask = mat ? mask2 : mask1;
  bf16* __restrict__ dst         = mat ? bT   : aT;

  const int tid  = threadIdx.x;
  const int lane = tid & 63;
  const int u    = tid >> 6;          // wave id 0..3 (c-quarter)
  const int r    = blockIdx.x & 255;
  const int s0   = (blockIdx.x >> 8) << 3;
  const int hp   = lane & 15;         // h-pair: h = 2*hp, 2*hp+1
  const int q    = lane >> 4;         // c sub-quarter

  // register-cached weight slice: w[c][2hp..2hp+1], c = u*64 + q*16 + e
  float2 wr[16];
  #pragma unroll
  for (int e = 0; e < 16; ++e) {
    const int c = u*64 + q*16 + e;
    wr[e] = *reinterpret_cast<const float2*>(w + c*H_DIM + hp*2);
  }

  // LayerNorm for this wave's 2 rows
  #pragma unroll
  for (int rr = 0; rr < 2; ++rr) {
    const int row = u*2 + rr;
    const int s = s0 + row;
    const float4 x = reinterpret_cast<const float4*>(m + ((size_t)s*R_DIM + r)*CM)[lane];
    float sum = x.x + x.y + x.z + x.w;
    float sq  = x.x*x.x + x.y*x.y + x.z*x.z + x.w*x.w;
    #pragma unroll
    for (int off = 1; off < 64; off <<= 1) {
      sum += __shfl_xor(sum, off);
      sq  += __shfl_xor(sq, off);
    }
    const float mu  = sum * (1.0f/CM);
    const float var = sq * (1.0f/CM) - mu*mu;
    const float rs  = rsqrtf(var + 1e-5f);
    const float4 lw = reinterpret_cast<const float4*>(lnw)[lane];
    const float4 lb = reinterpret_cast<const float4*>(lnbp)[lane];
    float4 v;
    v.x = (x.x - mu)*rs*lw.x + lb.x;
    v.y = (x.y - mu)*rs*lw.y + lb.y;
    v.z = (x.z - mu)*rs*lw.z + lb.z;
    v.w = (x.w - mu)*rs*lw.w + lb.w;
    *reinterpret_cast<float4*>(&xnb[row][lane*4]) = v;
  }
  __syncthreads();

  // dot: every wave covers its c-quarter of all 8 rows
  for (int row = 0; row < 8; ++row) {
    float a0 = 0.f, a1 = 0.f;
    #pragma unroll
    for (int e4 = 0; e4 < 4; ++e4) {
      const float4 xv = *reinterpret_cast<const float4*>(&xnb[row][u*64 + q*16 + e4*4]);
      a0 += xv.x*wr[e4*4+0].x + xv.y*wr[e4*4+1].x + xv.z*wr[e4*4+2].x + xv.w*wr[e4*4+3].x;
      a1 += xv.x*wr[e4*4+0].y + xv.y*wr[e4*4+1].y + xv.z*wr[e4*4+2].y + xv.w*wr[e4*4+3].y;
    }
    a0 += __shfl_xor(a0, 16); a0 += __shfl_xor(a0, 32);
    a1 += __shfl_xor(a1, 16); a1 += __shfl_xor(a1, 32);
    if (lane < 16)
      *reinterpret_cast<float2*>(&part[row][u][hp*2]) = make_float2(a0, a1);
  }
  __syncthreads();

  // combine 4 waves, +bias, *mask, convert to bf16
  {
    const int row = tid >> 5, h = tid & 31;
    float v = part[row][0][h] + part[row][1][h] + part[row][2][h] + part[row][3][h];
    const int s = s0 + row;
    v = (v + bias[h]) * mask[(size_t)s*R_DIM + r];
    valsb[row][h] = bf16_bits(v);
  }
  __syncthreads();

  // pack 8 s-values per h -> one 16B store
  if (tid < 32) {
    uint4 o;
    o.x = (unsigned)valsb[0][tid] | ((unsigned)valsb[1][tid] << 16);
    o.y = (unsigned)valsb[2][tid] | ((unsigned)valsb[3][tid] << 16);
    o.z = (unsigned)valsb[4][tid] | ((unsigned)valsb[5][tid] << 16);
    o.w = (unsigned)valsb[6][tid] | ((unsigned)valsb[7][tid] << 16);
    *reinterpret_cast<uint4*>(dst + ((size_t)(r*H_DIM + tid))*S_DIM + s0) = o;
  }
}

// ---------------------------------------------------------------------------
// Kernel 2: w_out [1024][128] fp32 -> w_outT [128 t][1024 ce] bf16
// ---------------------------------------------------------------------------
__global__ __launch_bounds__(256) void opm_wprep(const float* __restrict__ w_out,
                                                 bf16* __restrict__ wT)
{
  const int idx = blockIdx.x*256 + threadIdx.x;   // 131072 total
  const int ce = idx >> 7;
  const int t  = idx & 127;
  wT[t*1024 + ce] = __float2bfloat16(w_out[idx]);
}

// ---------------------------------------------------------------------------
// Kernel 3: rnorm[i][j] = 1 / (sum_s mask1[s,i]*mask2[s,j] + 1e-3)
// ---------------------------------------------------------------------------
__global__ __launch_bounds__(256) void opm_rnorm(const float* __restrict__ mask1,
                                                 const float* __restrict__ mask2,
                                                 float* __restrict__ rnorm)
{
  const int i = blockIdx.x;
  const int j = threadIdx.x;
  float acc = 0.f;
  for (int s = 0; s < S_DIM; ++s)
    acc += mask1[(size_t)s*R_DIM + i] * mask2[(size_t)s*R_DIM + j];
  rnorm[i*R_DIM + j] = 1.0f / (acc + 1e-3f);
}

// ---------------------------------------------------------------------------
// Kernel 4: fused GEMM1 (outer product, K=128) + epilogue GEMM (x w_out)
// WG: 256 thr = 4 waves, 128x128 Out1 tile = 16 (i,j) pairs; grid 64x64.
// ---------------------------------------------------------------------------
__global__ __launch_bounds__(256) void opm_gemm(
    const bf16* __restrict__ aT, const bf16* __restrict__ bT,
    const bf16* __restrict__ wT, const float* __restrict__ b_out,
    const float* __restrict__ rnorm, float* __restrict__ out)
{
  __shared__ char smem[65536];
  char* sA = smem;            // 32KB A tile, later reused as Oep [16][1024] bf16
  char* sB = smem + 32768;    // 32KB B tile

  const int tid  = threadIdx.x;
  const int lane = tid & 63;
  const int wid  = tid >> 6;
  const int bx = blockIdx.x, by = blockIdx.y;
  const int l15 = lane & 15;
  const int l4  = lane >> 4;

  // stage A,B tiles: 32KB each, fully contiguous in global (rows p0..p0+127)
  {
    const uint4* __restrict__ ga = reinterpret_cast<const uint4*>(aT + (size_t)bx*16384);
    const uint4* __restrict__ gb = reinterpret_cast<const uint4*>(bT + (size_t)by*16384);
    #pragma unroll
    for (int it = 0; it < 8; ++it) {
      const int idx = it*256 + tid;
      const int L  = idx << 4;                       // linear byte in [row(256B)][k]
      const int Ls = L ^ (((L >> 8) & 7) << 4);      // T2 XOR swizzle
      *reinterpret_cast<uint4*>(sA + Ls) = ga[idx];
      *reinterpret_cast<uint4*>(sB + Ls) = gb[idx];
    }
  }
  __syncthreads();

  const int wm = wid >> 1, wn = wid & 1;   // 2x2 waves, 64x64 each
  f32x4 acc[4][4];
  #pragma unroll
  for (int mf = 0; mf < 4; ++mf)
    #pragma unroll
    for (int nf = 0; nf < 4; ++nf)
      acc[mf][nf] = (f32x4){0.f, 0.f, 0.f, 0.f};

  #pragma unroll
  for (int ks = 0; ks < 4; ++ks) {
    s8v af[4], bfv[4];
    #pragma unroll
    for (int mf = 0; mf < 4; ++mf) {
      const int mm = wm*64 + mf*16 + l15;
      int L = mm*256 + ks*64 + l4*16;
      L ^= (mm & 7) << 4;
      af[mf] = *reinterpret_cast<const s8v*>(sA + L);
    }
    #pragma unroll
    for (int nf = 0; nf < 4; ++nf) {
      const int nn = wn*64 + nf*16 + l15;
      int L = nn*256 + ks*64 + l4*16;
      L ^= (nn & 7) << 4;
      bfv[nf] = *reinterpret_cast<const s8v*>(sB + L);
    }
    #pragma unroll
    for (int mf = 0; mf < 4; ++mf)
      #pragma unroll
      for (int nf = 0; nf < 4; ++nf)
        acc[mf][nf] = __builtin_amdgcn_mfma_f32_16x16x32_bf16(af[mf], bfv[nf], acc[mf][nf], 0, 0, 0);
  }
  __syncthreads();   // all reads of sA/sB done before Oep overwrite

  // write Out1 tile as bf16 Oep[pair][ce], pair=(m>>5)*4+(n>>5), ce=(m&31)*32+(n&31)
  #pragma unroll
  for (int mf = 0; mf < 4; ++mf) {
    #pragma unroll
    for (int nf = 0; nf < 4; ++nf) {
      #pragma unroll
      for (int j = 0; j < 4; ++j) {
        const int mm = wm*64 + mf*16 + l4*4 + j;   // C/D: row=(l>>4)*4+reg
        const int nn = wn*64 + nf*16 + l15;        // C/D: col=l&15
        const int pair = ((mm >> 5) << 2) | (nn >> 5);
        const int ce   = ((mm & 31) << 5) | (nn & 31);
        int L = pair*2048 + ce*2;
        L ^= (pair & 7) << 4;
        *reinterpret_cast<unsigned short*>(sA + L) = bf16_bits(acc[mf][nf][j]);
      }
    }
  }
  __syncthreads();

  // epilogue: [16 pairs x 1024] @ w_out[1024 x 128]; each wave: 32 t-cols
  {
    const int tb = wid*32;
    const float bv0 = b_out[tb + l15];
    const float bv1 = b_out[tb + 16 + l15];
    f32x4 e0 = {bv0, bv0, bv0, bv0};
    f32x4 e1 = {bv1, bv1, bv1, bv1};
    const bf16* __restrict__ wp0 = wT + (size_t)(tb + l15)*1024 + l4*8;
    const bf16* __restrict__ wp1 = wT + (size_t)(tb + 16 + l15)*1024 + l4*8;
    #pragma unroll 8
    for (int ks = 0; ks < 32; ++ks) {
      const int row = l15;                       // A row = pair
      int L = row*2048 + ks*64 + l4*16;
      L ^= (row & 7) << 4;
      const s8v a   = *reinterpret_cast<const s8v*>(sA + L);
      const s8v bw0 = *reinterpret_cast<const s8v*>(wp0 + ks*32);
      const s8v bw1 = *reinterpret_cast<const s8v*>(wp1 + ks*32);
      e0 = __builtin_amdgcn_mfma_f32_16x16x32_bf16(a, bw0, e0, 0, 0, 0);
      e1 = __builtin_amdgcn_mfma_f32_16x16x32_bf16(a, bw1, e1, 0, 0, 0);
    }
    #pragma unroll
    for (int j = 0; j < 4; ++j) {
      const int pair = l4*4 + j;                 // D: row=(l>>4)*4+reg
      const int ig = bx*4 + (pair >> 2);
      const int jg = by*4 + (pair & 3);
      const int o = ig*R_DIM + jg;
      const float rn = rnorm[o];
      out[(size_t)o*CZ + tb + l15]      = e0[j] * rn;
      out[(size_t)o*CZ + tb + 16 + l15] = e1[j] * rn;
    }
  }
}

// ---------------------------------------------------------------------------
extern "C" void kernel_launch(void* const* d_in, const int* in_sizes, int n_in,
                              void* d_out, int out_size, void* d_ws, size_t ws_size,
                              hipStream_t stream) {
  const float* m_1    = (const float*)d_in[0];
  const float* m_2    = (const float*)d_in[1];
  const float* mask_1 = (const float*)d_in[2];
  const float* mask_2 = (const float*)d_in[3];
  const float* ln1_w  = (const float*)d_in[4];
  const float* ln1_b  = (const float*)d_in[5];
  const float* ln2_w  = (const float*)d_in[6];
  const float* ln2_b  = (const float*)d_in[7];
  const float* w1     = (const float*)d_in[8];
  const float* b1     = (const float*)d_in[9];
  const float* w2     = (const float*)d_in[10];
  const float* b2     = (const float*)d_in[11];
  const float* w_out  = (const float*)d_in[12];
  const float* b_out  = (const float*)d_in[13];
  float* out = (float*)d_out;

  char* ws = (char*)d_ws;
  bf16* aT    = (bf16*)ws;                              // 2 MB  [8192][128]
  bf16* bT    = (bf16*)(ws + (2u << 20));               // 2 MB
  bf16* wT    = (bf16*)(ws + (4u << 20));               // 256 KB [128][1024]
  float* rnrm = (float*)(ws + (4u << 20) + (256u << 10)); // 256 KB [256][256]
  // total ws use: 4.75 MB

  opm_proj <<<dim3(4096, 2), dim3(256), 0, stream>>>(m_1, m_2, ln1_w, ln1_b,
      ln2_w, ln2_b, w1, b1, w2, b2, mask_1, mask_2, aT, bT);
  opm_wprep<<<dim3(512),     dim3(256), 0, stream>>>(w_out, wT);
  opm_rnorm<<<dim3(256),     dim3(256), 0, stream>>>(mask_1, mask_2, rnrm);
  opm_gemm <<<dim3(64, 64),  dim3(256), 0, stream>>>(aT, bT, wT, b_out, rnrm, out);
}

// Round 2
// 100.269 us; speedup vs baseline: 1.8584x; 1.8584x over previous
//
#include <hip/hip_runtime.h>
#include <hip/hip_bf16.h>

#define S_DIM 128
#define R_DIM 256
#define CM    256
#define H_DIM 32
#define CZ    128

typedef short s8v   __attribute__((ext_vector_type(8)));   // 8 bf16 in 4 VGPRs
typedef float f32x4 __attribute__((ext_vector_type(4)));
typedef float f32x16 __attribute__((ext_vector_type(16)));
using bf16 = __hip_bfloat16;

static __device__ __forceinline__ unsigned short bf16_bits(float f) {
  return __builtin_bit_cast(unsigned short, __float2bfloat16(f));
}

static __device__ __forceinline__ void gload_lds16(const void* g, void* l) {
  __builtin_amdgcn_global_load_lds(
      (const __attribute__((address_space(1))) unsigned int*)g,
      (__attribute__((address_space(3))) unsigned int*)l, 16, 0, 0);
}

// ---------------------------------------------------------------------------
// Kernel 1: fused LayerNorm + linear + mask -> transposed bf16, PRE-SWIZZLED:
// aT[p][128 s] with 16B-chunk cs stored at cs ^ (p&7)  (p = r*32 + h).
// ---------------------------------------------------------------------------
__global__ __launch_bounds__(256) void opm_proj(
    const float* __restrict__ m1, const float* __restrict__ m2,
    const float* __restrict__ ln1w, const float* __restrict__ ln1b,
    const float* __restrict__ ln2w, const float* __restrict__ ln2b,
    const float* __restrict__ w1, const float* __restrict__ b1,
    const float* __restrict__ w2, const float* __restrict__ b2,
    const float* __restrict__ mask1, const float* __restrict__ mask2,
    bf16* __restrict__ aT, bf16* __restrict__ bT)
{
  __shared__ float xnb[8][CM];
  __shared__ float part[8][4][H_DIM];
  __shared__ unsigned short valsb[8][H_DIM];

  const int mat = blockIdx.y;
  const float* __restrict__ m    = mat ? m2   : m1;
  const float* __restrict__ lnw  = mat ? ln2w : ln1w;
  const float* __restrict__ lnbp = mat ? ln2b : ln1b;
  const float* __restrict__ w    = mat ? w2   : w1;
  const float* __restrict__ bias = mat ? b2   : b1;
  const float* __restrict__ mask = mat ? mask2 : mask1;
  bf16* __restrict__ dst         = mat ? bT   : aT;

  const int tid  = threadIdx.x;
  const int lane = tid & 63;
  const int u    = tid >> 6;
  const int r    = blockIdx.x & 255;
  const int s0   = (blockIdx.x >> 8) << 3;
  const int hp   = lane & 15;
  const int q    = lane >> 4;

  float2 wr[16];
  #pragma unroll
  for (int e = 0; e < 16; ++e) {
    const int c = u*64 + q*16 + e;
    wr[e] = *reinterpret_cast<const float2*>(w + c*H_DIM + hp*2);
  }

  #pragma unroll
  for (int rr = 0; rr < 2; ++rr) {
    const int row = u*2 + rr;
    const int s = s0 + row;
    const float4 x = reinterpret_cast<const float4*>(m + ((size_t)s*R_DIM + r)*CM)[lane];
    float sum = x.x + x.y + x.z + x.w;
    float sq  = x.x*x.x + x.y*x.y + x.z*x.z + x.w*x.w;
    #pragma unroll
    for (int off = 1; off < 64; off <<= 1) {
      sum += __shfl_xor(sum, off);
      sq  += __shfl_xor(sq, off);
    }
    const float mu  = sum * (1.0f/CM);
    const float var = sq * (1.0f/CM) - mu*mu;
    const float rs  = rsqrtf(var + 1e-5f);
    const float4 lw = reinterpret_cast<const float4*>(lnw)[lane];
    const float4 lb = reinterpret_cast<const float4*>(lnbp)[lane];
    float4 v;
    v.x = (x.x - mu)*rs*lw.x + lb.x;
    v.y = (x.y - mu)*rs*lw.y + lb.y;
    v.z = (x.z - mu)*rs*lw.z + lb.z;
    v.w = (x.w - mu)*rs*lw.w + lb.w;
    *reinterpret_cast<float4*>(&xnb[row][lane*4]) = v;
  }
  __syncthreads();

  for (int row = 0; row < 8; ++row) {
    float a0 = 0.f, a1 = 0.f;
    #pragma unroll
    for (int e4 = 0; e4 < 4; ++e4) {
      const float4 xv = *reinterpret_cast<const float4*>(&xnb[row][u*64 + q*16 + e4*4]);
      a0 += xv.x*wr[e4*4+0].x + xv.y*wr[e4*4+1].x + xv.z*wr[e4*4+2].x + xv.w*wr[e4*4+3].x;
      a1 += xv.x*wr[e4*4+0].y + xv.y*wr[e4*4+1].y + xv.z*wr[e4*4+2].y + xv.w*wr[e4*4+3].y;
    }
    a0 += __shfl_xor(a0, 16); a0 += __shfl_xor(a0, 32);
    a1 += __shfl_xor(a1, 16); a1 += __shfl_xor(a1, 32);
    if (lane < 16)
      *reinterpret_cast<float2*>(&part[row][u][hp*2]) = make_float2(a0, a1);
  }
  __syncthreads();

  {
    const int row = tid >> 5, h = tid & 31;
    float v = part[row][0][h] + part[row][1][h] + part[row][2][h] + part[row][3][h];
    const int s = s0 + row;
    v = (v + bias[h]) * mask[(size_t)s*R_DIM + r];
    valsb[row][h] = bf16_bits(v);
  }
  __syncthreads();

  if (tid < 32) {
    uint4 o;
    o.x = (unsigned)valsb[0][tid] | ((unsigned)valsb[1][tid] << 16);
    o.y = (unsigned)valsb[2][tid] | ((unsigned)valsb[3][tid] << 16);
    o.z = (unsigned)valsb[4][tid] | ((unsigned)valsb[5][tid] << 16);
    o.w = (unsigned)valsb[6][tid] | ((unsigned)valsb[7][tid] << 16);
    const int p  = r*H_DIM + tid;
    const int cs = (s0 >> 3) ^ (p & 7);          // pre-swizzled chunk position
    *reinterpret_cast<uint4*>(dst + (size_t)p*S_DIM + cs*8) = o;
  }
}

// ---------------------------------------------------------------------------
// Kernel 2: gather w_out [1024][128] fp32 into exact B-fragment order (bf16):
// wT2 vector v = (tb*64+ks2)*64+lane holds elems e=0..7 with
//   t = tb*32 + (lane&31),  ce' = ks2*16 + (lane>>5)*8 + e,
//   w_out row = (ce'&31)*32 + (ce'>>5)     (ce' = e_dim*32 + c_dim)
// ---------------------------------------------------------------------------
__global__ __launch_bounds__(256) void opm_wprep(const float* __restrict__ w_out,
                                                 bf16* __restrict__ wT2)
{
  const int vid  = blockIdx.x*256 + threadIdx.x;   // 16384 vectors
  const int lane = vid & 63;
  const int ks2  = (vid >> 6) & 63;
  const int tb   = vid >> 12;
  const int t    = tb*32 + (lane & 31);
  const int hf   = lane >> 5;
  unsigned int pk[4];
  #pragma unroll
  for (int ep = 0; ep < 4; ++ep) {
    unsigned int w0, w1;
    {
      const int cep = ks2*16 + hf*8 + ep*2;
      w0 = bf16_bits(w_out[((cep & 31)*32 + (cep >> 5))*CZ + t]);
    }
    {
      const int cep = ks2*16 + hf*8 + ep*2 + 1;
      w1 = bf16_bits(w_out[((cep & 31)*32 + (cep >> 5))*CZ + t]);
    }
    pk[ep] = w0 | (w1 << 16);
  }
  uint4 o = {pk[0], pk[1], pk[2], pk[3]};
  *reinterpret_cast<uint4*>((char*)wT2 + (size_t)vid*16) = o;
}

// ---------------------------------------------------------------------------
// Kernel 3: rnorm[i][j] = 1 / (sum_s mask1[s,i]*mask2[s,j] + 1e-3)
// ---------------------------------------------------------------------------
__global__ __launch_bounds__(256) void opm_rnorm(const float* __restrict__ mask1,
                                                 const float* __restrict__ mask2,
                                                 float* __restrict__ rnorm)
{
  const int i = blockIdx.x;
  const int j = threadIdx.x;
  float acc = 0.f;
  for (int s = 0; s < S_DIM; ++s)
    acc += mask1[(size_t)s*R_DIM + i] * mask2[(size_t)s*R_DIM + j];
  rnorm[i*R_DIM + j] = 1.0f / (acc + 1e-3f);
}

// ---------------------------------------------------------------------------
// Kernel 4: 256x256 Out1 tile (64 (i,j) pairs) fused with epilogue GEMM.
// 8 waves; LDS 128KB: A[256][128]+B[256][128] bf16 -> reused as Oep[64][1024].
// ---------------------------------------------------------------------------
__global__ __launch_bounds__(512, 2) void opm_gemm(
    const bf16* __restrict__ aT, const bf16* __restrict__ bT,
    const bf16* __restrict__ wT2, const float* __restrict__ b_out,
    const float* __restrict__ rnorm, float* __restrict__ out)
{
  __shared__ char smem[131072];

  const int tid  = threadIdx.x;
  const int lane = tid & 63;
  const int wid  = tid >> 6;
  const int l31  = lane & 31;
  const int hf   = lane >> 5;

  // XCD-aware bijective swizzle (1024 % 8 == 0)
  int swz = blockIdx.x;
  swz = (swz & 7)*128 + (swz >> 3);
  const int bx = swz >> 5, by = swz & 31;

  // ---- stage A,B tiles (pre-swizzled global -> linear LDS, 16B async) ----
  {
    const char* gA = (const char*)aT + (size_t)bx*65536;
    const char* gB = (const char*)bT + (size_t)by*65536;
    #pragma unroll
    for (int i = 0; i < 8; ++i) {
      const int base = (i*8 + wid)*1024;
      gload_lds16(gA + base + lane*16, smem + base);
      gload_lds16(gB + base + lane*16, smem + 65536 + base);
    }
  }
  __syncthreads();

  // ---- GEMM1: per wave 128x64 sub-tile, 32x32x16 MFMAs, K=128 ----
  const int wm = wid >> 2, wn = wid & 3;
  f32x16 acc[4][2];
  #pragma unroll
  for (int mf = 0; mf < 4; ++mf)
    #pragma unroll
    for (int nf = 0; nf < 2; ++nf)
      #pragma unroll
      for (int r = 0; r < 16; ++r) acc[mf][nf][r] = 0.f;

  #pragma unroll
  for (int ks = 0; ks < 8; ++ks) {
    s8v af[4], bfv[2];
    #pragma unroll
    for (int mf = 0; mf < 4; ++mf) {
      const int mm = wm*128 + mf*32 + l31;
      int L = mm*256 + ks*32 + hf*16;
      L ^= (mm & 7) << 4;
      af[mf] = *reinterpret_cast<const s8v*>(smem + L);
    }
    #pragma unroll
    for (int nf = 0; nf < 2; ++nf) {
      const int nn = wn*64 + nf*32 + l31;
      int L = nn*256 + ks*32 + hf*16;
      L ^= (nn & 7) << 4;
      bfv[nf] = *reinterpret_cast<const s8v*>(smem + 65536 + L);
    }
    #pragma unroll
    for (int mf = 0; mf < 4; ++mf)
      #pragma unroll
      for (int nf = 0; nf < 2; ++nf)
        acc[mf][nf] = __builtin_amdgcn_mfma_f32_32x32x16_bf16(af[mf], bfv[nf], acc[mf][nf], 0, 0, 0);
  }
  __syncthreads();   // all LDS reads of A/B done

  // ---- write Oep[pair][ce'] bf16, ce' = e*32 + c, packed ds_write_b64 ----
  // byte L0 = pair*2048 + ce'*2; physical = L0 ^ (((pair&7)^((L0>>7)&7))<<4)
  #pragma unroll
  for (int mf = 0; mf < 4; ++mf) {
    #pragma unroll
    for (int nf = 0; nf < 2; ++nf) {
      const int pair = (wm*4 + mf)*8 + wn*2 + nf;
      #pragma unroll
      for (int g = 0; g < 4; ++g) {
        const unsigned int lo = (unsigned)bf16_bits(acc[mf][nf][4*g+0]) |
                                ((unsigned)bf16_bits(acc[mf][nf][4*g+1]) << 16);
        const unsigned int hi = (unsigned)bf16_bits(acc[mf][nf][4*g+2]) |
                                ((unsigned)bf16_bits(acc[mf][nf][4*g+3]) << 16);
        const int L0 = pair*2048 + (l31*32 + 8*g + 4*hf)*2;
        const int L  = L0 ^ ((((pair & 7) ^ ((L0 >> 7) & 7))) << 4);
        uint2 v; v.x = lo; v.y = hi;
        *reinterpret_cast<uint2*>(smem + L) = v;
      }
    }
  }
  __syncthreads();

  // ---- epilogue: waves 0..3; wave w: all 64 pairs x t-block w (32 t) ----
  if (wid < 4) {
    const int t = wid*32 + l31;
    const float bo = b_out[t];
    f32x16 z0, z1;
    #pragma unroll
    for (int r = 0; r < 16; ++r) { z0[r] = bo; z1[r] = bo; }

    const char* wb = (const char*)wT2 + ((size_t)(wid*64)*64 + lane)*16;
    #pragma unroll 8
    for (int ks2 = 0; ks2 < 64; ++ks2) {
      const s8v bw = *reinterpret_cast<const s8v*>(wb + ks2*1024);
      {
        const int pair = l31;                       // mf2 = 0
        int L0 = pair*2048 + ks2*32 + hf*16;
        int L  = L0 ^ ((((pair & 7) ^ ((L0 >> 7) & 7))) << 4);
        const s8v a = *reinterpret_cast<const s8v*>(smem + L);
        z0 = __builtin_amdgcn_mfma_f32_32x32x16_bf16(a, bw, z0, 0, 0, 0);
      }
      {
        const int pair = 32 + l31;                  // mf2 = 1
        int L0 = pair*2048 + ks2*32 + hf*16;
        int L  = L0 ^ ((((pair & 7) ^ ((L0 >> 7) & 7))) << 4);
        const s8v a = *reinterpret_cast<const s8v*>(smem + L);
        z1 = __builtin_amdgcn_mfma_f32_32x32x16_bf16(a, bw, z1, 0, 0, 0);
      }
    }

    #pragma unroll
    for (int r = 0; r < 16; ++r) {
      const int row = (r & 3) + 8*(r >> 2) + 4*hf;
      {
        const int pair = row;                       // mf2 = 0
        const int o = (bx*8 + (pair >> 3))*R_DIM + by*8 + (pair & 7);
        out[(size_t)o*CZ + t] = z0[r] * rnorm[o];
      }
      {
        const int pair = 32 + row;                  // mf2 = 1
        const int o = (bx*8 + (pair >> 3))*R_DIM + by*8 + (pair & 7);
        out[(size_t)o*CZ + t] = z1[r] * rnorm[o];
      }
    }
  }
}

// ---------------------------------------------------------------------------
extern "C" void kernel_launch(void* const* d_in, const int* in_sizes, int n_in,
                              void* d_out, int out_size, void* d_ws, size_t ws_size,
                              hipStream_t stream) {
  const float* m_1    = (const float*)d_in[0];
  const float* m_2    = (const float*)d_in[1];
  const float* mask_1 = (const float*)d_in[2];
  const float* mask_2 = (const float*)d_in[3];
  const float* ln1_w  = (const float*)d_in[4];
  const float* ln1_b  = (const float*)d_in[5];
  const float* ln2_w  = (const float*)d_in[6];
  const float* ln2_b  = (const float*)d_in[7];
  const float* w1     = (const float*)d_in[8];
  const float* b1     = (const float*)d_in[9];
  const float* w2     = (const float*)d_in[10];
  const float* b2     = (const float*)d_in[11];
  const float* w_out  = (const float*)d_in[12];
  const float* b_out  = (const float*)d_in[13];
  float* out = (float*)d_out;

  char* ws = (char*)d_ws;
  bf16* aT    = (bf16*)ws;                               // 2 MB  [8192][128], pre-swizzled
  bf16* bT    = (bf16*)(ws + (2u << 20));                // 2 MB
  bf16* wT2   = (bf16*)(ws + (4u << 20));                // 256 KB fragment-ordered
  float* rnrm = (float*)(ws + (4u << 20) + (256u << 10)); // 256 KB

  opm_proj <<<dim3(4096, 2), dim3(256), 0, stream>>>(m_1, m_2, ln1_w, ln1_b,
      ln2_w, ln2_b, w1, b1, w2, b2, mask_1, mask_2, aT, bT);
  opm_wprep<<<dim3(64),      dim3(256), 0, stream>>>(w_out, wT2);
  opm_rnorm<<<dim3(256),     dim3(256), 0, stream>>>(mask_1, mask_2, rnrm);
  opm_gemm <<<dim3(1024),    dim3(512), 0, stream>>>(aT, bT, wT2, b_out, rnrm, out);
}

// Round 3
// 77.453 us; speedup vs baseline: 2.4058x; 1.2946x over previous
//
#include <hip/hip_runtime.h>
#include <hip/hip_bf16.h>

#define S_DIM 128
#define R_DIM 256
#define CM    256
#define H_DIM 32
#define CZ    128

typedef short s8v   __attribute__((ext_vector_type(8)));   // 8 bf16 in 4 VGPRs
typedef float f32x4 __attribute__((ext_vector_type(4)));
typedef float f32x16 __attribute__((ext_vector_type(16)));
using bf16 = __hip_bfloat16;

static __device__ __forceinline__ unsigned short bf16_bits(float f) {
  return __builtin_bit_cast(unsigned short, __float2bfloat16(f));
}

static __device__ __forceinline__ void gload_lds16(const void* g, void* l) {
  __builtin_amdgcn_global_load_lds(
      (const __attribute__((address_space(1))) unsigned int*)g,
      (__attribute__((address_space(3))) unsigned int*)l, 16, 0, 0);
}

// ---------------------------------------------------------------------------
// Kernel 0 (prep, one launch):
//  blocks 0..63   : w_out [1024][128] fp32 -> wT2 bf16 in epilogue B-frag order
//  blocks 64..319 : rnorm[i][j] = 1/(sum_s mask1[s,i]*mask2[s,j] + 1e-3)
//  blocks 320..321: w1/w2 [256][32] fp32 -> wF bf16 in proj B-frag order
// ---------------------------------------------------------------------------
__global__ __launch_bounds__(256) void opm_prep(
    const float* __restrict__ w_out,
    const float* __restrict__ mask1, const float* __restrict__ mask2,
    const float* __restrict__ w1, const float* __restrict__ w2,
    bf16* __restrict__ wT2, float* __restrict__ rnorm, bf16* __restrict__ wF)
{
  const int b   = blockIdx.x;
  const int tid = threadIdx.x;
  if (b < 64) {
    // wT2 vector v = (tb*64+ks2)*64+lane: t = tb*32+(lane&31),
    // k = ks2*16+(lane>>5)*8+e, w_out row = (k&31)*32 + (k>>5)
    const int vid  = b*256 + tid;
    const int lane = vid & 63;
    const int ks2  = (vid >> 6) & 63;
    const int tb   = vid >> 12;
    const int t    = tb*32 + (lane & 31);
    const int hf   = lane >> 5;
    unsigned int pk[4];
    #pragma unroll
    for (int ep = 0; ep < 4; ++ep) {
      const int ce0 = ks2*16 + hf*8 + ep*2;
      const int ce1 = ce0 + 1;
      unsigned int w0 = bf16_bits(w_out[((ce0 & 31)*32 + (ce0 >> 5))*CZ + t]);
      unsigned int w1b = bf16_bits(w_out[((ce1 & 31)*32 + (ce1 >> 5))*CZ + t]);
      pk[ep] = w0 | (w1b << 16);
    }
    uint4 o = {pk[0], pk[1], pk[2], pk[3]};
    *reinterpret_cast<uint4*>((char*)wT2 + (size_t)vid*16) = o;
  } else if (b < 320) {
    const int i = b - 64;
    const int j = tid;
    float acc = 0.f;
    for (int s = 0; s < S_DIM; ++s)
      acc += mask1[(size_t)s*R_DIM + i] * mask2[(size_t)s*R_DIM + j];
    rnorm[i*R_DIM + j] = 1.0f / (acc + 1e-3f);
  } else {
    // wF[mat] vector v = (nf*8+ks)*64+lane: h = nf*16+(lane&15),
    // k(c) = ks*32 + (lane>>4)*8 + e
    const int mat = b - 320;
    const float* __restrict__ w = mat ? w2 : w1;
    bf16* __restrict__ dst = wF + mat*8192;
    #pragma unroll
    for (int it = 0; it < 4; ++it) {
      const int vid  = it*256 + tid;
      const int nf   = vid >> 9;
      const int ks   = (vid >> 6) & 7;
      const int lane = vid & 63;
      const int h    = nf*16 + (lane & 15);
      unsigned int pk[4];
      #pragma unroll
      for (int ep = 0; ep < 4; ++ep) {
        const int c0 = ks*32 + (lane >> 4)*8 + ep*2;
        unsigned int lo = bf16_bits(w[c0*H_DIM + h]);
        unsigned int hi = bf16_bits(w[(c0 + 1)*H_DIM + h]);
        pk[ep] = lo | (hi << 16);
      }
      uint4 o = {pk[0], pk[1], pk[2], pk[3]};
      *reinterpret_cast<uint4*>((char*)dst + (size_t)vid*16) = o;
    }
  }
}

// ---------------------------------------------------------------------------
// Kernel 1 (proj): 1 wave per block, 16 rows (s0..s0+15, r) of one matrix.
// LN (4-lane reduce) -> bf16 LDS (XOR swizzle) -> 16x mfma 16x16x32 vs wF
// -> +bias, *mask -> packed 8B pre-swizzled stores into aT/bT[p][s].
// ---------------------------------------------------------------------------
__global__ __launch_bounds__(64) void opm_proj(
    const float* __restrict__ m1, const float* __restrict__ m2,
    const float* __restrict__ ln1w, const float* __restrict__ ln1b,
    const float* __restrict__ ln2w, const float* __restrict__ ln2b,
    const float* __restrict__ b1, const float* __restrict__ b2,
    const float* __restrict__ mask1, const float* __restrict__ mask2,
    const bf16* __restrict__ wF, bf16* __restrict__ aT, bf16* __restrict__ bT)
{
  __shared__ char xn[8192];   // [16 s][256 c] bf16, byte ^ ((s&7)<<4)

  const int mat = blockIdx.y;
  const float* __restrict__ m    = mat ? m2   : m1;
  const float* __restrict__ lnw  = mat ? ln2w : ln1w;
  const float* __restrict__ lnb  = mat ? ln2b : ln1b;
  const float* __restrict__ bias = mat ? b2   : b1;
  const float* __restrict__ mask = mat ? mask2 : mask1;
  const bf16* __restrict__ wf    = wF + mat*8192;
  bf16* __restrict__ dst         = mat ? bT   : aT;

  const int lane = threadIdx.x;
  const int row  = lane & 15;      // s' index (and later MFMA A-row / D-col)
  const int q    = lane >> 4;      // c-quarter (and later k-slice / D row grp)
  const int r    = blockIdx.x & 255;
  const int sb   = blockIdx.x >> 8;
  const int s    = sb*16 + row;

  // ---- load 64 contiguous floats of row (s, r) ----
  const float4* __restrict__ src =
      reinterpret_cast<const float4*>(m + ((size_t)s*R_DIM + r)*CM + q*64);
  float4 x[16];
  float sum = 0.f, sq = 0.f;
  #pragma unroll
  for (int i = 0; i < 16; ++i) {
    x[i] = src[i];
    sum += x[i].x + x[i].y + x[i].z + x[i].w;
    sq  += x[i].x*x[i].x + x[i].y*x[i].y + x[i].z*x[i].z + x[i].w*x[i].w;
  }
  sum += __shfl_xor(sum, 16); sum += __shfl_xor(sum, 32);
  sq  += __shfl_xor(sq, 16);  sq  += __shfl_xor(sq, 32);
  const float mu = sum * (1.0f/CM);
  const float rs = rsqrtf(sq * (1.0f/CM) - mu*mu + 1e-5f);

  // ---- normalize + ln affine -> bf16 -> LDS ----
  const float4* __restrict__ lw4 = reinterpret_cast<const float4*>(lnw + q*64);
  const float4* __restrict__ lb4 = reinterpret_cast<const float4*>(lnb + q*64);
  #pragma unroll
  for (int i2 = 0; i2 < 8; ++i2) {
    unsigned int pk[4];
    #pragma unroll
    for (int half = 0; half < 2; ++half) {
      const int i = i2*2 + half;
      const float4 lw = lw4[i];
      const float4 lb = lb4[i];
      const float v0 = (x[i].x - mu)*rs*lw.x + lb.x;
      const float v1 = (x[i].y - mu)*rs*lw.y + lb.y;
      const float v2 = (x[i].z - mu)*rs*lw.z + lb.z;
      const float v3 = (x[i].w - mu)*rs*lw.w + lb.w;
      pk[half*2+0] = (unsigned)bf16_bits(v0) | ((unsigned)bf16_bits(v1) << 16);
      pk[half*2+1] = (unsigned)bf16_bits(v2) | ((unsigned)bf16_bits(v3) << 16);
    }
    int off = row*512 + q*128 + i2*16;
    off ^= (row & 7) << 4;
    uint4 o = {pk[0], pk[1], pk[2], pk[3]};
    *reinterpret_cast<uint4*>(xn + off) = o;
  }
  __syncthreads();

  // ---- MFMA: [16 s x 256 c] @ w[256 c x 32 h] ----
  const float bv0 = bias[row];
  const float bv1 = bias[16 + row];
  f32x4 z0 = {bv0, bv0, bv0, bv0};
  f32x4 z1 = {bv1, bv1, bv1, bv1};
  #pragma unroll
  for (int ks = 0; ks < 8; ++ks) {
    int off = row*512 + ks*64 + q*16;
    off ^= (row & 7) << 4;
    const s8v a  = *reinterpret_cast<const s8v*>(xn + off);
    const s8v w0 = *reinterpret_cast<const s8v*>((const char*)wf + (ks*64 + lane)*16);
    const s8v w1 = *reinterpret_cast<const s8v*>((const char*)wf + ((8 + ks)*64 + lane)*16);
    z0 = __builtin_amdgcn_mfma_f32_16x16x32_bf16(a, w0, z0, 0, 0, 0);
    z1 = __builtin_amdgcn_mfma_f32_16x16x32_bf16(a, w1, z1, 0, 0, 0);
  }

  // ---- epilogue: *mask, bf16, packed 8B pre-swizzled stores ----
  // D: col = lane&15 (h offset), row' = q*4 + reg  (s = sb*16 + row')
  float mk[4];
  #pragma unroll
  for (int rr = 0; rr < 4; ++rr)
    mk[rr] = mask[(size_t)(sb*16 + q*4 + rr)*R_DIM + r];

  unsigned int pa0 = (unsigned)bf16_bits(z0[0]*mk[0]) | ((unsigned)bf16_bits(z0[1]*mk[1]) << 16);
  unsigned int pa1 = (unsigned)bf16_bits(z0[2]*mk[2]) | ((unsigned)bf16_bits(z0[3]*mk[3]) << 16);
  unsigned int pb0 = (unsigned)bf16_bits(z1[0]*mk[0]) | ((unsigned)bf16_bits(z1[1]*mk[1]) << 16);
  unsigned int pb1 = (unsigned)bf16_bits(z1[2]*mk[2]) | ((unsigned)bf16_bits(z1[3]*mk[3]) << 16);

  const int p0 = r*H_DIM + row;        // h = row
  const int p1 = r*H_DIM + 16 + row;   // h = 16 + row
  const int c0 = sb*2 + (q >> 1);      // 16B chunk index along s
  const int rem = (q & 1) * 8;
  {
    uint2 v; v.x = pa0; v.y = pa1;
    *reinterpret_cast<uint2*>((char*)dst + (size_t)p0*256 + ((c0 ^ (p0 & 7)) << 4) + rem) = v;
  }
  {
    uint2 v; v.x = pb0; v.y = pb1;
    *reinterpret_cast<uint2*>((char*)dst + (size_t)p1*256 + ((c0 ^ (p1 & 7)) << 4) + rem) = v;
  }
}

// ---------------------------------------------------------------------------
// Kernel 2 (gemm): 256x256 Out1 tile (64 (i,j) pairs) fused with epilogue.
// 8 waves; LDS 128KB: A[256][128]+B[256][128] bf16 -> reused as Oep[64][1024].
// Epilogue: all 8 waves (2 pair-blocks x 4 t-blocks), 2-chain ILP.
// ---------------------------------------------------------------------------
__global__ __launch_bounds__(512, 2) void opm_gemm(
    const bf16* __restrict__ aT, const bf16* __restrict__ bT,
    const bf16* __restrict__ wT2, const float* __restrict__ b_out,
    const float* __restrict__ rnorm, float* __restrict__ out)
{
  __shared__ char smem[131072];

  const int tid  = threadIdx.x;
  const int lane = tid & 63;
  const int wid  = tid >> 6;
  const int l31  = lane & 31;
  const int hf   = lane >> 5;

  // XCD-aware bijective swizzle (1024 % 8 == 0)
  int swz = blockIdx.x;
  swz = (swz & 7)*128 + (swz >> 3);
  const int bx = swz >> 5, by = swz & 31;

  // ---- stage A,B tiles (pre-swizzled global -> linear LDS, 16B async) ----
  {
    const char* gA = (const char*)aT + (size_t)bx*65536;
    const char* gB = (const char*)bT + (size_t)by*65536;
    #pragma unroll
    for (int i = 0; i < 8; ++i) {
      const int base = (i*8 + wid)*1024;
      gload_lds16(gA + base + lane*16, smem + base);
      gload_lds16(gB + base + lane*16, smem + 65536 + base);
    }
  }
  __syncthreads();

  // ---- GEMM1: per wave 128x64 sub-tile, 32x32x16 MFMAs, K=128 ----
  const int wm = wid >> 2, wn = wid & 3;
  f32x16 acc[4][2];
  #pragma unroll
  for (int mf = 0; mf < 4; ++mf)
    #pragma unroll
    for (int nf = 0; nf < 2; ++nf)
      #pragma unroll
      for (int r = 0; r < 16; ++r) acc[mf][nf][r] = 0.f;

  #pragma unroll
  for (int ks = 0; ks < 8; ++ks) {
    s8v af[4], bfv[2];
    #pragma unroll
    for (int mf = 0; mf < 4; ++mf) {
      const int mm = wm*128 + mf*32 + l31;
      int L = mm*256 + ks*32 + hf*16;
      L ^= (mm & 7) << 4;
      af[mf] = *reinterpret_cast<const s8v*>(smem + L);
    }
    #pragma unroll
    for (int nf = 0; nf < 2; ++nf) {
      const int nn = wn*64 + nf*32 + l31;
      int L = nn*256 + ks*32 + hf*16;
      L ^= (nn & 7) << 4;
      bfv[nf] = *reinterpret_cast<const s8v*>(smem + 65536 + L);
    }
    #pragma unroll
    for (int mf = 0; mf < 4; ++mf)
      #pragma unroll
      for (int nf = 0; nf < 2; ++nf)
        acc[mf][nf] = __builtin_amdgcn_mfma_f32_32x32x16_bf16(af[mf], bfv[nf], acc[mf][nf], 0, 0, 0);
  }
  __syncthreads();   // all LDS reads of A/B done

  // ---- write Oep[pair][ce'] bf16, ce' = e*32 + c, packed ds_write_b64 ----
  #pragma unroll
  for (int mf = 0; mf < 4; ++mf) {
    #pragma unroll
    for (int nf = 0; nf < 2; ++nf) {
      const int pair = (wm*4 + mf)*8 + wn*2 + nf;
      #pragma unroll
      for (int g = 0; g < 4; ++g) {
        const unsigned int lo = (unsigned)bf16_bits(acc[mf][nf][4*g+0]) |
                                ((unsigned)bf16_bits(acc[mf][nf][4*g+1]) << 16);
        const unsigned int hi = (unsigned)bf16_bits(acc[mf][nf][4*g+2]) |
                                ((unsigned)bf16_bits(acc[mf][nf][4*g+3]) << 16);
        const int L0 = pair*2048 + (l31*32 + 8*g + 4*hf)*2;
        const int L  = L0 ^ ((((pair & 7) ^ ((L0 >> 7) & 7))) << 4);
        uint2 v; v.x = lo; v.y = hi;
        *reinterpret_cast<uint2*>(smem + L) = v;
      }
    }
  }
  __syncthreads();

  // ---- epilogue: 8 waves: pm = pair-block (2), pn = t-block (4) ----
  {
    const int pm = wid >> 2, pn = wid & 3;
    const int t  = pn*32 + l31;
    const float bo = b_out[t];
    f32x16 ze, zo;
    #pragma unroll
    for (int r = 0; r < 16; ++r) { ze[r] = bo; zo[r] = 0.f; }

    const char* wb = (const char*)wT2 + ((size_t)(pn*64)*64 + lane)*16;
    const int pair = pm*32 + l31;
    #pragma unroll 8
    for (int ks2 = 0; ks2 < 64; ++ks2) {
      const s8v bw = *reinterpret_cast<const s8v*>(wb + ks2*1024);
      int L0 = pair*2048 + ks2*32 + hf*16;
      int L  = L0 ^ ((((pair & 7) ^ ((L0 >> 7) & 7))) << 4);
      const s8v a = *reinterpret_cast<const s8v*>(smem + L);
      if (ks2 & 1)
        zo = __builtin_amdgcn_mfma_f32_32x32x16_bf16(a, bw, zo, 0, 0, 0);
      else
        ze = __builtin_amdgcn_mfma_f32_32x32x16_bf16(a, bw, ze, 0, 0, 0);
    }

    #pragma unroll
    for (int r = 0; r < 16; ++r) {
      const float z = ze[r] + zo[r];
      const int row = (r & 3) + 8*(r >> 2) + 4*hf;
      const int pr  = pm*32 + row;
      const int o   = (bx*8 + (pr >> 3))*R_DIM + by*8 + (pr & 7);
      out[(size_t)o*CZ + t] = z * rnorm[o];
    }
  }
}

// ---------------------------------------------------------------------------
extern "C" void kernel_launch(void* const* d_in, const int* in_sizes, int n_in,
                              void* d_out, int out_size, void* d_ws, size_t ws_size,
                              hipStream_t stream) {
  const float* m_1    = (const float*)d_in[0];
  const float* m_2    = (const float*)d_in[1];
  const float* mask_1 = (const float*)d_in[2];
  const float* mask_2 = (const float*)d_in[3];
  const float* ln1_w  = (const float*)d_in[4];
  const float* ln1_b  = (const float*)d_in[5];
  const float* ln2_w  = (const float*)d_in[6];
  const float* ln2_b  = (const float*)d_in[7];
  const float* w1     = (const float*)d_in[8];
  const float* b1     = (const float*)d_in[9];
  const float* w2     = (const float*)d_in[10];
  const float* b2     = (const float*)d_in[11];
  const float* w_out  = (const float*)d_in[12];
  const float* b_out  = (const float*)d_in[13];
  float* out = (float*)d_out;

  char* ws = (char*)d_ws;
  bf16* aT    = (bf16*)ws;                                  // 2 MB, pre-swizzled
  bf16* bT    = (bf16*)(ws + (2u << 20));                   // 2 MB
  bf16* wT2   = (bf16*)(ws + (4u << 20));                   // 256 KB frag-ordered
  float* rnrm = (float*)(ws + (4u << 20) + (256u << 10));   // 256 KB
  bf16* wF    = (bf16*)(ws + (4u << 20) + (512u << 10));    // 32 KB proj w frags

  opm_prep<<<dim3(322),      dim3(256), 0, stream>>>(w_out, mask_1, mask_2,
      w1, w2, wT2, rnrm, wF);
  opm_proj<<<dim3(2048, 2),  dim3(64),  0, stream>>>(m_1, m_2, ln1_w, ln1_b,
      ln2_w, ln2_b, b1, b2, mask_1, mask_2, wF, aT, bT);
  opm_gemm<<<dim3(1024),     dim3(512), 0, stream>>>(aT, bT, wT2, b_out, rnrm, out);
}

// Round 4
// 74.533 us; speedup vs baseline: 2.5001x; 1.0392x over previous
//
#include <hip/hip_runtime.h>
#include <hip/hip_bf16.h>

#define S_DIM 128
#define R_DIM 256
#define CM    256
#define H_DIM 32
#define CZ    128

typedef short s8v   __attribute__((ext_vector_type(8)));   // 8 bf16 in 4 VGPRs
typedef float f32x4 __attribute__((ext_vector_type(4)));
typedef float f32x16 __attribute__((ext_vector_type(16)));
using bf16 = __hip_bfloat16;

static __device__ __forceinline__ unsigned short bf16_bits(float f) {
  return __builtin_bit_cast(unsigned short, __float2bfloat16(f));
}

static __device__ __forceinline__ void gload_lds16(const void* g, void* l) {
  __builtin_amdgcn_global_load_lds(
      (const __attribute__((address_space(1))) unsigned int*)g,
      (__attribute__((address_space(3))) unsigned int*)l, 16, 0, 0);
}

// ---------------------------------------------------------------------------
// Kernel 0 (prep, one launch):
//  blocks 0..63   : w_out [1024][128] fp32 -> wT2 bf16 in epilogue B-frag order
//  blocks 64..319 : rnorm[i][j] = 1/(sum_s mask1[s,i]*mask2[s,j] + 1e-3)
//  blocks 320..321: w1/w2 [256][32] fp32 -> wF bf16 in proj B-frag order
// ---------------------------------------------------------------------------
__global__ __launch_bounds__(256) void opm_prep(
    const float* __restrict__ w_out,
    const float* __restrict__ mask1, const float* __restrict__ mask2,
    const float* __restrict__ w1, const float* __restrict__ w2,
    bf16* __restrict__ wT2, float* __restrict__ rnorm, bf16* __restrict__ wF)
{
  const int b   = blockIdx.x;
  const int tid = threadIdx.x;
  if (b < 64) {
    const int vid  = b*256 + tid;
    const int lane = vid & 63;
    const int ks2  = (vid >> 6) & 63;
    const int tb   = vid >> 12;
    const int t    = tb*32 + (lane & 31);
    const int hf   = lane >> 5;
    unsigned int pk[4];
    #pragma unroll
    for (int ep = 0; ep < 4; ++ep) {
      const int ce0 = ks2*16 + hf*8 + ep*2;
      const int ce1 = ce0 + 1;
      unsigned int w0 = bf16_bits(w_out[((ce0 & 31)*32 + (ce0 >> 5))*CZ + t]);
      unsigned int w1b = bf16_bits(w_out[((ce1 & 31)*32 + (ce1 >> 5))*CZ + t]);
      pk[ep] = w0 | (w1b << 16);
    }
    uint4 o = {pk[0], pk[1], pk[2], pk[3]};
    *reinterpret_cast<uint4*>((char*)wT2 + (size_t)vid*16) = o;
  } else if (b < 320) {
    const int i = b - 64;
    const int j = tid;
    float acc = 0.f;
    for (int s = 0; s < S_DIM; ++s)
      acc += mask1[(size_t)s*R_DIM + i] * mask2[(size_t)s*R_DIM + j];
    rnorm[i*R_DIM + j] = 1.0f / (acc + 1e-3f);
  } else {
    const int mat = b - 320;
    const float* __restrict__ w = mat ? w2 : w1;
    bf16* __restrict__ dst = wF + mat*8192;
    #pragma unroll
    for (int it = 0; it < 4; ++it) {
      const int vid  = it*256 + tid;
      const int nf   = vid >> 9;
      const int ks   = (vid >> 6) & 7;
      const int lane = vid & 63;
      const int h    = nf*16 + (lane & 15);
      unsigned int pk[4];
      #pragma unroll
      for (int ep = 0; ep < 4; ++ep) {
        const int c0 = ks*32 + (lane >> 4)*8 + ep*2;
        unsigned int lo = bf16_bits(w[c0*H_DIM + h]);
        unsigned int hi = bf16_bits(w[(c0 + 1)*H_DIM + h]);
        pk[ep] = lo | (hi << 16);
      }
      uint4 o = {pk[0], pk[1], pk[2], pk[3]};
      *reinterpret_cast<uint4*>((char*)dst + (size_t)vid*16) = o;
    }
  }
}

// ---------------------------------------------------------------------------
// Kernel 1 (proj): 1 wave per block, 16 rows (s0..s0+15, r) of one matrix.
// LN (4-lane reduce) -> bf16 LDS (XOR swizzle) -> 16x mfma 16x16x32 vs wF
// -> +bias, *mask -> packed 8B stores, global pre-swizzle chunk ^= (p&15).
// ---------------------------------------------------------------------------
__global__ __launch_bounds__(64) void opm_proj(
    const float* __restrict__ m1, const float* __restrict__ m2,
    const float* __restrict__ ln1w, const float* __restrict__ ln1b,
    const float* __restrict__ ln2w, const float* __restrict__ ln2b,
    const float* __restrict__ b1, const float* __restrict__ b2,
    const float* __restrict__ mask1, const float* __restrict__ mask2,
    const bf16* __restrict__ wF, bf16* __restrict__ aT, bf16* __restrict__ bT)
{
  __shared__ char xn[8192];   // [16 s][256 c] bf16, byte ^ ((s&7)<<4)

  const int mat = blockIdx.y;
  const float* __restrict__ m    = mat ? m2   : m1;
  const float* __restrict__ lnw  = mat ? ln2w : ln1w;
  const float* __restrict__ lnb  = mat ? ln2b : ln1b;
  const float* __restrict__ bias = mat ? b2   : b1;
  const float* __restrict__ mask = mat ? mask2 : mask1;
  const bf16* __restrict__ wf    = wF + mat*8192;
  bf16* __restrict__ dst         = mat ? bT   : aT;

  const int lane = threadIdx.x;
  const int row  = lane & 15;
  const int q    = lane >> 4;
  const int r    = blockIdx.x & 255;
  const int sb   = blockIdx.x >> 8;
  const int s    = sb*16 + row;

  const float4* __restrict__ src =
      reinterpret_cast<const float4*>(m + ((size_t)s*R_DIM + r)*CM + q*64);
  float4 x[16];
  float sum = 0.f, sq = 0.f;
  #pragma unroll
  for (int i = 0; i < 16; ++i) {
    x[i] = src[i];
    sum += x[i].x + x[i].y + x[i].z + x[i].w;
    sq  += x[i].x*x[i].x + x[i].y*x[i].y + x[i].z*x[i].z + x[i].w*x[i].w;
  }
  sum += __shfl_xor(sum, 16); sum += __shfl_xor(sum, 32);
  sq  += __shfl_xor(sq, 16);  sq  += __shfl_xor(sq, 32);
  const float mu = sum * (1.0f/CM);
  const float rs = rsqrtf(sq * (1.0f/CM) - mu*mu + 1e-5f);

  const float4* __restrict__ lw4 = reinterpret_cast<const float4*>(lnw + q*64);
  const float4* __restrict__ lb4 = reinterpret_cast<const float4*>(lnb + q*64);
  #pragma unroll
  for (int i2 = 0; i2 < 8; ++i2) {
    unsigned int pk[4];
    #pragma unroll
    for (int half = 0; half < 2; ++half) {
      const int i = i2*2 + half;
      const float4 lw = lw4[i];
      const float4 lb = lb4[i];
      const float v0 = (x[i].x - mu)*rs*lw.x + lb.x;
      const float v1 = (x[i].y - mu)*rs*lw.y + lb.y;
      const float v2 = (x[i].z - mu)*rs*lw.z + lb.z;
      const float v3 = (x[i].w - mu)*rs*lw.w + lb.w;
      pk[half*2+0] = (unsigned)bf16_bits(v0) | ((unsigned)bf16_bits(v1) << 16);
      pk[half*2+1] = (unsigned)bf16_bits(v2) | ((unsigned)bf16_bits(v3) << 16);
    }
    int off = row*512 + q*128 + i2*16;
    off ^= (row & 7) << 4;
    uint4 o = {pk[0], pk[1], pk[2], pk[3]};
    *reinterpret_cast<uint4*>(xn + off) = o;
  }
  __syncthreads();

  const float bv0 = bias[row];
  const float bv1 = bias[16 + row];
  f32x4 z0 = {bv0, bv0, bv0, bv0};
  f32x4 z1 = {bv1, bv1, bv1, bv1};
  #pragma unroll
  for (int ks = 0; ks < 8; ++ks) {
    int off = row*512 + ks*64 + q*16;
    off ^= (row & 7) << 4;
    const s8v a  = *reinterpret_cast<const s8v*>(xn + off);
    const s8v w0 = *reinterpret_cast<const s8v*>((const char*)wf + (ks*64 + lane)*16);
    const s8v w1 = *reinterpret_cast<const s8v*>((const char*)wf + ((8 + ks)*64 + lane)*16);
    z0 = __builtin_amdgcn_mfma_f32_16x16x32_bf16(a, w0, z0, 0, 0, 0);
    z1 = __builtin_amdgcn_mfma_f32_16x16x32_bf16(a, w1, z1, 0, 0, 0);
  }

  float mk[4];
  #pragma unroll
  for (int rr = 0; rr < 4; ++rr)
    mk[rr] = mask[(size_t)(sb*16 + q*4 + rr)*R_DIM + r];

  unsigned int pa0 = (unsigned)bf16_bits(z0[0]*mk[0]) | ((unsigned)bf16_bits(z0[1]*mk[1]) << 16);
  unsigned int pa1 = (unsigned)bf16_bits(z0[2]*mk[2]) | ((unsigned)bf16_bits(z0[3]*mk[3]) << 16);
  unsigned int pb0 = (unsigned)bf16_bits(z1[0]*mk[0]) | ((unsigned)bf16_bits(z1[1]*mk[1]) << 16);
  unsigned int pb1 = (unsigned)bf16_bits(z1[2]*mk[2]) | ((unsigned)bf16_bits(z1[3]*mk[3]) << 16);

  const int p0 = r*H_DIM + row;
  const int p1 = r*H_DIM + 16 + row;
  const int c0 = sb*2 + (q >> 1);      // 16B chunk index along s (0..15)
  const int rem = (q & 1) * 8;
  {
    uint2 v; v.x = pa0; v.y = pa1;
    *reinterpret_cast<uint2*>((char*)dst + (size_t)p0*256 + ((c0 ^ (p0 & 15)) << 4) + rem) = v;
  }
  {
    uint2 v; v.x = pb0; v.y = pb1;
    *reinterpret_cast<uint2*>((char*)dst + (size_t)p1*256 + ((c0 ^ (p1 & 15)) << 4) + rem) = v;
  }
}

// ---------------------------------------------------------------------------
// Kernel 2 (gemm): 256x256 Out1 tile (64 pairs) fused with epilogue.
// 8 waves; LDS 128KB: A+B staging -> reused as Oep[64][1024] -> reused zred.
// Epilogue: waves (kh 2 x pn 4): both pair-blocks, half the ks2 range each
// (each wT2 fragment loaded exactly once -> 256KB L2/WG), LDS reduce at end.
// ---------------------------------------------------------------------------
__global__ __launch_bounds__(512, 2) void opm_gemm(
    const bf16* __restrict__ aT, const bf16* __restrict__ bT,
    const bf16* __restrict__ wT2, const float* __restrict__ b_out,
    const float* __restrict__ rnorm, float* __restrict__ out)
{
  __shared__ char smem[131072];

  const int tid  = threadIdx.x;
  const int lane = tid & 63;
  const int wid  = tid >> 6;
  const int l31  = lane & 31;
  const int hf   = lane >> 5;

  // XCD-aware bijective swizzle (1024 % 8 == 0)
  int swz = blockIdx.x;
  swz = (swz & 7)*128 + (swz >> 3);
  const int bx = swz >> 5, by = swz & 31;

  // ---- stage A,B tiles (pre-swizzled global -> linear LDS, 16B async) ----
  {
    const char* gA = (const char*)aT + (size_t)bx*65536;
    const char* gB = (const char*)bT + (size_t)by*65536;
    #pragma unroll
    for (int i = 0; i < 8; ++i) {
      const int base = (i*8 + wid)*1024;
      gload_lds16(gA + base + lane*16, smem + base);
      gload_lds16(gB + base + lane*16, smem + 65536 + base);
    }
  }
  __syncthreads();

  // ---- GEMM1: per wave 128x64 sub-tile, 32x32x16 MFMAs, K=128 ----
  const int wm = wid >> 2, wn = wid & 3;
  f32x16 acc[4][2];
  #pragma unroll
  for (int mf = 0; mf < 4; ++mf)
    #pragma unroll
    for (int nf = 0; nf < 2; ++nf)
      #pragma unroll
      for (int r = 0; r < 16; ++r) acc[mf][nf][r] = 0.f;

  #pragma unroll
  for (int ks = 0; ks < 8; ++ks) {
    s8v af[4], bfv[2];
    #pragma unroll
    for (int mf = 0; mf < 4; ++mf) {
      const int mm = wm*128 + mf*32 + l31;
      int L = (mm*256 + ks*32 + hf*16) ^ ((mm & 15) << 4);
      af[mf] = *reinterpret_cast<const s8v*>(smem + L);
    }
    #pragma unroll
    for (int nf = 0; nf < 2; ++nf) {
      const int nn = wn*64 + nf*32 + l31;
      int L = (nn*256 + ks*32 + hf*16) ^ ((nn & 15) << 4);
      bfv[nf] = *reinterpret_cast<const s8v*>(smem + 65536 + L);
    }
    #pragma unroll
    for (int mf = 0; mf < 4; ++mf)
      #pragma unroll
      for (int nf = 0; nf < 2; ++nf)
        acc[mf][nf] = __builtin_amdgcn_mfma_f32_32x32x16_bf16(af[mf], bfv[nf], acc[mf][nf], 0, 0, 0);
  }
  __syncthreads();   // all LDS reads of A/B done

  // ---- write Oep[pair][ce'] bf16 (ce' = e*32 + c), packed ds_write_b64 ----
  // L0 = pair*2048 + ce'*2; physical = L0 ^ (((pair&15)^((L0>>7)&15))<<4)
  #pragma unroll
  for (int mf = 0; mf < 4; ++mf) {
    #pragma unroll
    for (int nf = 0; nf < 2; ++nf) {
      const int pair = (wm*4 + mf)*8 + wn*2 + nf;
      #pragma unroll
      for (int g = 0; g < 4; ++g) {
        const unsigned int lo = (unsigned)bf16_bits(acc[mf][nf][4*g+0]) |
                                ((unsigned)bf16_bits(acc[mf][nf][4*g+1]) << 16);
        const unsigned int hi = (unsigned)bf16_bits(acc[mf][nf][4*g+2]) |
                                ((unsigned)bf16_bits(acc[mf][nf][4*g+3]) << 16);
        const int L0 = pair*2048 + (l31*32 + 8*g + 4*hf)*2;
        const int L  = L0 ^ ((((pair & 15) ^ ((L0 >> 7) & 15))) << 4);
        uint2 v; v.x = lo; v.y = hi;
        *reinterpret_cast<uint2*>(smem + L) = v;
      }
    }
  }
  __syncthreads();

  // ---- epilogue: waves (kh = wid>>2, pn = wid&3) ----
  const int kh = wid >> 2, pn = wid & 3;
  const int t  = pn*32 + l31;
  f32x16 z0, z1;
  {
    const float init = (kh == 0) ? b_out[t] : 0.f;
    #pragma unroll
    for (int r = 0; r < 16; ++r) { z0[r] = init; z1[r] = init; }
  }
  {
    const char* wb = (const char*)wT2 + ((size_t)(pn*64 + kh*32)*64 + lane)*16;
    #pragma unroll 8
    for (int ks = 0; ks < 32; ++ks) {
      const int ks2 = kh*32 + ks;
      const s8v bw = *reinterpret_cast<const s8v*>(wb + ks*1024);
      {
        const int pair = l31;
        int L0 = pair*2048 + ks2*32 + hf*16;
        int L  = L0 ^ ((((pair & 15) ^ ((L0 >> 7) & 15))) << 4);
        const s8v a = *reinterpret_cast<const s8v*>(smem + L);
        z0 = __builtin_amdgcn_mfma_f32_32x32x16_bf16(a, bw, z0, 0, 0, 0);
      }
      {
        const int pair = 32 + l31;
        int L0 = pair*2048 + ks2*32 + hf*16;
        int L  = L0 ^ ((((pair & 15) ^ ((L0 >> 7) & 15))) << 4);
        const s8v a = *reinterpret_cast<const s8v*>(smem + L);
        z1 = __builtin_amdgcn_mfma_f32_32x32x16_bf16(a, bw, z1, 0, 0, 0);
      }
    }
  }
  __syncthreads();   // Oep dead; reuse LDS for partials

  // ---- kh=1 waves deposit partials: [pn][pm][g][lane] 16B each ----
  if (kh == 1) {
    #pragma unroll
    for (int g = 0; g < 4; ++g) {
      f32x4 v0 = {z0[4*g+0], z0[4*g+1], z0[4*g+2], z0[4*g+3]};
      f32x4 v1 = {z1[4*g+0], z1[4*g+1], z1[4*g+2], z1[4*g+3]};
      *reinterpret_cast<f32x4*>(smem + pn*16384 +        g*1024 + lane*16) = v0;
      *reinterpret_cast<f32x4*>(smem + pn*16384 + 8192 + g*1024 + lane*16) = v1;
    }
  }
  __syncthreads();

  // ---- kh=0 waves reduce + scale + store ----
  if (kh == 0) {
    #pragma unroll
    for (int g = 0; g < 4; ++g) {
      const f32x4 p0 = *reinterpret_cast<const f32x4*>(smem + pn*16384 +        g*1024 + lane*16);
      const f32x4 p1 = *reinterpret_cast<const f32x4*>(smem + pn*16384 + 8192 + g*1024 + lane*16);
      #pragma unroll
      for (int j = 0; j < 4; ++j) { z0[4*g+j] += p0[j]; z1[4*g+j] += p1[j]; }
    }
    #pragma unroll
    for (int r = 0; r < 16; ++r) {
      const int row = (r & 3) + 8*(r >> 2) + 4*hf;
      {
        const int pr = row;
        const int o  = (bx*8 + (pr >> 3))*R_DIM + by*8 + (pr & 7);
        out[(size_t)o*CZ + t] = z0[r] * rnorm[o];
      }
      {
        const int pr = 32 + row;
        const int o  = (bx*8 + (pr >> 3))*R_DIM + by*8 + (pr & 7);
        out[(size_t)o*CZ + t] = z1[r] * rnorm[o];
      }
    }
  }
}

// ---------------------------------------------------------------------------
extern "C" void kernel_launch(void* const* d_in, const int* in_sizes, int n_in,
                              void* d_out, int out_size, void* d_ws, size_t ws_size,
                              hipStream_t stream) {
  const float* m_1    = (const float*)d_in[0];
  const float* m_2    = (const float*)d_in[1];
  const float* mask_1 = (const float*)d_in[2];
  const float* mask_2 = (const float*)d_in[3];
  const float* ln1_w  = (const float*)d_in[4];
  const float* ln1_b  = (const float*)d_in[5];
  const float* ln2_w  = (const float*)d_in[6];
  const float* ln2_b  = (const float*)d_in[7];
  const float* w1     = (const float*)d_in[8];
  const float* b1     = (const float*)d_in[9];
  const float* w2     = (const float*)d_in[10];
  const float* b2     = (const float*)d_in[11];
  const float* w_out  = (const float*)d_in[12];
  const float* b_out  = (const float*)d_in[13];
  float* out = (float*)d_out;

  char* ws = (char*)d_ws;
  bf16* aT    = (bf16*)ws;                                  // 2 MB, pre-swizzled
  bf16* bT    = (bf16*)(ws + (2u << 20));                   // 2 MB
  bf16* wT2   = (bf16*)(ws + (4u << 20));                   // 256 KB frag-ordered
  float* rnrm = (float*)(ws + (4u << 20) + (256u << 10));   // 256 KB
  bf16* wF    = (bf16*)(ws + (4u << 20) + (512u << 10));    // 32 KB proj w frags

  opm_prep<<<dim3(322),      dim3(256), 0, stream>>>(w_out, mask_1, mask_2,
      w1, w2, wT2, rnrm, wF);
  opm_proj<<<dim3(2048, 2),  dim3(64),  0, stream>>>(m_1, m_2, ln1_w, ln1_b,
      ln2_w, ln2_b, b1, b2, mask_1, mask_2, wF, aT, bT);
  opm_gemm<<<dim3(1024),     dim3(512), 0, stream>>>(aT, bT, wT2, b_out, rnrm, out);
}